// Round 4
// baseline (151.852 us; speedup 1.0000x reference)
//
#include <hip/hip_runtime.h>

#define EPSF 1e-7f

typedef float v4f __attribute__((ext_vector_type(4)));
typedef float v2f __attribute__((ext_vector_type(2)));

// asm global load: guaranteed register residency (not rematerializable),
// program-order pinned (volatile) so counted vmcnt waits are exact.
__device__ __forceinline__ void gl4(v4f& d, const float* p) {
    asm volatile("global_load_dwordx4 %0, %1, off" : "=v"(d) : "v"(p));
}
template<int OFF>
__device__ __forceinline__ void gl4o(v4f& d, const float* p) {
    asm volatile("global_load_dwordx4 %0, %1, off offset:%2"
                 : "=v"(d) : "v"(p), "i"(OFF));
}
// packed fp32 FMA: 2 MACs per instruction (volatile: must stay after waitcnt).
__device__ __forceinline__ void pkfma(v2f& acc, v2f a, v2f b) {
    asm volatile("v_pk_fma_f32 %0, %1, %2, %0" : "+v"(acc) : "v"(a), "v"(b));
}

template<int CTRL>
__device__ __forceinline__ float dpp_add(float x) {
    int sh = __builtin_amdgcn_update_dpp(0, __float_as_int(x), CTRL, 0xF, 0xF, true);
    return x + __int_as_float(sh);
}
// all-reduce over lane bits 0..3 (16-lane row): xor1,2,7,15 span GF(2)^4.
__device__ __forceinline__ float row16_allsum(float x) {
    x = dpp_add<0xB1>(x);
    x = dpp_add<0x4E>(x);
    x = dpp_add<0x141>(x);
    x = dpp_add<0x140>(x);
    return x;
}
// all-reduce over lane bits 4,5.
__device__ __forceinline__ float gquad_allsum(float x) {
    x += __int_as_float(__builtin_amdgcn_ds_swizzle(__float_as_int(x), 0x401F)); // xor16
    x += __shfl_xor(x, 32, 64);                                                  // xor32
    return x;
}

// B=8, predict-m=32, K=256, routing-im=32, OD=16, IND=8, YK*XK=4.
// Grid: 1024 blocks = 256 (b*32+m) x 4 k-slices of 64. Block: 512 threads (8 waves).
__global__ __launch_bounds__(512, 4)
void caps_fused(const float* __restrict__ pc,   // [8,32,32,32,8]
                const float* __restrict__ Wt,   // [8,32,1,2,2,32,16,8]
                const float* __restrict__ bL,   // [1,32,16,16,32]
                float* __restrict__ out)        // [8,32,16,16,16]
{
    const int bid = blockIdx.x;
    const int bm  = bid >> 2;          // b*32 + m
    const int ks  = bid & 3;           // k-slice of 64
    const int om  = bm & 31;

    const int t    = threadIdx.x;
    const int wav  = t >> 6;
    const int lane = t & 63;
    const int g    = lane >> 4;        // phase 2: owns im 8g..8g+7
    const int od   = lane & 15;
    const int imw  = t >> 4;           // phase 1 W ownership
    const int odw  = t & 15;

    // ---- W fragment: 32 floats = 8 x dwordx4, pinned in VGPRs via asm ----
    v4f wv[8];
    {
        const float* wb = Wt + (size_t)bm * 16384 + (size_t)((imw << 4) + odw) * 8;
        #pragma unroll
        for (int yx = 0; yx < 4; ++yx) {
            gl4o<0>(wv[yx*2+0], wb + yx*4096);
            gl4o<16>(wv[yx*2+1], wb + yx*4096);
        }
    }
    asm volatile("s_waitcnt vmcnt(0)");

    const float* pcb = pc  + (size_t)bm * 8192;   // [k][32] fp32
    const float* bLb = bL  + (size_t)om * 8192;   // [k][32]
    float*       ob  = out + (size_t)bm * 4096;   // [k][16]

    __shared__ float s_x[2][8][512];

    const int k_lo = ks << 6;

    for (int c = 0; c < 8; ++c) {
        const int k0 = k_lo + (c << 3);
        const int p  = c & 1;
        const int k  = k0 + wav;

        // ---- issue bbv loads first (drained by the h=0 wait) ----
        v4f bb0, bb1;
        {
            const float* bp = bLb + (k << 5) + (g << 3);
            gl4o<0>(bb0, bp);
            gl4o<16>(bb1, bp);
        }

        // ---- phase 1: 16 half-tiles (16 floats each), depth-2 vmcnt pipeline ----
        const float* xb = pcb + (size_t)k0 * 32;   // chunk base; offsets 0..1008 B
        v4f sl[2][4];
        #pragma unroll
        for (int q = 0; q < 4; ++q) gl4o<0>(sl[0][q], xb + q*4);   // dummy offsets below
        // (re-issue with correct immediates: half0 = bytes 0..63, half1 = 64..127)
        // NOTE: the loop above loaded half0 with offset 0 only at q=0; fix by
        // explicit issues:
        gl4o<16>(sl[0][1], xb);
        gl4o<32>(sl[0][2], xb);
        gl4o<48>(sl[0][3], xb);
        gl4o<64>(sl[1][0], xb);
        gl4o<80>(sl[1][1], xb);
        gl4o<96>(sl[1][2], xb);
        gl4o<112>(sl[1][3], xb);

        v2f acca, accb;
        #pragma unroll
        for (int h = 0; h < 16; ++h) {
            if (h < 15) asm volatile("s_waitcnt vmcnt(4)");
            else        asm volatile("s_waitcnt vmcnt(0)");
            const int hh = h & 1;
            if (hh == 0) { acca.x = 0.f; acca.y = 0.f; accb.x = 0.f; accb.y = 0.f; }
            #pragma unroll
            for (int q = 0; q < 4; ++q) {
                pkfma(acca, wv[hh*4+q].xy, sl[hh][q].xy);
                pkfma(accb, wv[hh*4+q].zw, sl[hh][q].zw);
            }
            if (hh == 1) {
                float acc = (acca.x + acca.y) + (accb.x + accb.y);
                s_x[p][h >> 1][(imw << 4) + odw] = acc;
            }
            if (h < 14) {
                // prefetch half h+2 into the slot just consumed
                switch (h + 2) {
                    case 2:  gl4o<128>(sl[hh][0], xb); gl4o<144>(sl[hh][1], xb); gl4o<160>(sl[hh][2], xb); gl4o<176>(sl[hh][3], xb); break;
                    case 3:  gl4o<192>(sl[hh][0], xb); gl4o<208>(sl[hh][1], xb); gl4o<224>(sl[hh][2], xb); gl4o<240>(sl[hh][3], xb); break;
                    case 4:  gl4o<256>(sl[hh][0], xb); gl4o<272>(sl[hh][1], xb); gl4o<288>(sl[hh][2], xb); gl4o<304>(sl[hh][3], xb); break;
                    case 5:  gl4o<320>(sl[hh][0], xb); gl4o<336>(sl[hh][1], xb); gl4o<352>(sl[hh][2], xb); gl4o<368>(sl[hh][3], xb); break;
                    case 6:  gl4o<384>(sl[hh][0], xb); gl4o<400>(sl[hh][1], xb); gl4o<416>(sl[hh][2], xb); gl4o<432>(sl[hh][3], xb); break;
                    case 7:  gl4o<448>(sl[hh][0], xb); gl4o<464>(sl[hh][1], xb); gl4o<480>(sl[hh][2], xb); gl4o<496>(sl[hh][3], xb); break;
                    case 8:  gl4o<512>(sl[hh][0], xb); gl4o<528>(sl[hh][1], xb); gl4o<544>(sl[hh][2], xb); gl4o<560>(sl[hh][3], xb); break;
                    case 9:  gl4o<576>(sl[hh][0], xb); gl4o<592>(sl[hh][1], xb); gl4o<608>(sl[hh][2], xb); gl4o<624>(sl[hh][3], xb); break;
                    case 10: gl4o<640>(sl[hh][0], xb); gl4o<656>(sl[hh][1], xb); gl4o<672>(sl[hh][2], xb); gl4o<688>(sl[hh][3], xb); break;
                    case 11: gl4o<704>(sl[hh][0], xb); gl4o<720>(sl[hh][1], xb); gl4o<736>(sl[hh][2], xb); gl4o<752>(sl[hh][3], xb); break;
                    case 12: gl4o<768>(sl[hh][0], xb); gl4o<784>(sl[hh][1], xb); gl4o<800>(sl[hh][2], xb); gl4o<816>(sl[hh][3], xb); break;
                    case 13: gl4o<832>(sl[hh][0], xb); gl4o<848>(sl[hh][1], xb); gl4o<864>(sl[hh][2], xb); gl4o<880>(sl[hh][3], xb); break;
                    case 14: gl4o<896>(sl[hh][0], xb); gl4o<912>(sl[hh][1], xb); gl4o<928>(sl[hh][2], xb); gl4o<944>(sl[hh][3], xb); break;
                    case 15: gl4o<960>(sl[hh][0], xb); gl4o<976>(sl[hh][1], xb); gl4o<992>(sl[hh][2], xb); gl4o<1008>(sl[hh][3], xb); break;
                }
            }
        }

        __syncthreads();

        // ---------- phase 2: wave `wav` routes tile k (validated r2 logic) ----------
        float xu[8];
        #pragma unroll
        for (int j = 0; j < 8; ++j)
            xu[j] = s_x[p][wav][((g * 8 + j) << 4) + od];

        float bbv[8] = {bb0.x, bb0.y, bb0.z, bb0.w, bb1.x, bb1.y, bb1.z, bb1.w};

        float vv = 0.f;
        #pragma unroll
        for (int r = 0; r < 3; ++r) {
            float e[8], S = 0.f;
            #pragma unroll
            for (int j = 0; j < 8; ++j) { e[j] = __expf(bbv[j]); S += e[j]; }
            S = gquad_allsum(S);
            float inv = __builtin_amdgcn_rcpf(S);

            vv = 0.f;
            #pragma unroll
            for (int j = 0; j < 8; ++j) vv = fmaf(e[j], xu[j], vv);
            vv = gquad_allsum(vv) * inv;

            float sq = row16_allsum(vv * vv);
            float scale = sq * __builtin_amdgcn_rcpf(1.f + sq) * rsqrtf(sq + EPSF);
            vv *= scale;

            if (r < 2) {
                #pragma unroll
                for (int j = 0; j < 8; ++j)
                    bbv[j] += row16_allsum(xu[j] * vv);
            }
        }

        if (g == 0)
            asm volatile("global_store_dword %0, %1, off"
                         :: "v"(ob + (k << 4) + od), "v"(vv) : "memory");
    }
}

extern "C" void kernel_launch(void* const* d_in, const int* in_sizes, int n_in,
                              void* d_out, int out_size, void* d_ws, size_t ws_size,
                              hipStream_t stream)
{
    const float* pc = (const float*)d_in[0];
    const float* Wt = (const float*)d_in[1];
    const float* bL = (const float*)d_in[2];
    float*       o  = (float*)d_out;
    caps_fused<<<dim3(1024), dim3(512), 0, stream>>>(pc, Wt, bL, o);
}

// Round 5
// 56.316 us; speedup vs baseline: 2.6964x; 2.6964x over previous
//
#include <hip/hip_runtime.h>

#define EPSF 1e-7f

typedef short bf16x8 __attribute__((ext_vector_type(8)));
typedef float f32x4  __attribute__((ext_vector_type(4)));

__device__ __forceinline__ short bf_hi(float f) {
    return (short)(__float_as_uint(f) >> 16);        // truncation; residual exact in f32
}
__device__ __forceinline__ float bf_to_f(short h) {
    return __uint_as_float(((unsigned)(unsigned short)h) << 16);
}

template<int CTRL>
__device__ __forceinline__ float dpp_add(float x) {
    int sh = __builtin_amdgcn_update_dpp(0, __float_as_int(x), CTRL, 0xF, 0xF, true);
    return x + __int_as_float(sh);
}
// all-reduce over lane bits 0..3 (16-lane row): xor1,2,7,15 span GF(2)^4.
__device__ __forceinline__ float row16_allsum(float x) {
    x = dpp_add<0xB1>(x);   // xor 1
    x = dpp_add<0x4E>(x);   // xor 2
    x = dpp_add<0x141>(x);  // xor 7
    x = dpp_add<0x140>(x);  // xor 15
    return x;
}
// all-reduce over lane bits 4,5.
__device__ __forceinline__ float gquad_allsum(float x) {
    x += __int_as_float(__builtin_amdgcn_ds_swizzle(__float_as_int(x), 0x401F)); // xor16
    x += __shfl_xor(x, 32, 64);                                                  // xor32
    return x;
}

#define XSTR 516   // LDS row stride: 2-way (free) C-store conflicts, 4-way xu reads

// B=8, predict-m=32, K=256, routing-im=32, OD=16, k-contraction=(yx,e)=32.
// Grid: 1024 blocks = 256 (b*32+m) x 4 k-slices of 64. Block: 512 threads (8 waves).
// Phase 1 (per 16-k chunk): MFMA 16x16x32 bf16, 3-term hi/lo split for fp32 accuracy.
//   A = x_in[16 k][32 (yx,e)], B = W[32 (yx,e)][512 (im,od)]; wave w owns n in [64w,64w+64).
// Phase 2: wave w routes tiles m=2w,2w+1 with the validated r2 DPP routing.
__global__ __launch_bounds__(512, 4)
void caps_fused(const float* __restrict__ pc,   // [8,32,32,32,8]
                const float* __restrict__ Wt,   // [8,32,1,2,2,32,16,8]
                const float* __restrict__ bL,   // [1,32,16,16,32]
                float* __restrict__ out)        // [8,32,16,16,16]
{
    const int bid = blockIdx.x;
    const int bm  = bid >> 2;          // b*32 + m
    const int ks  = bid & 3;           // k-slice of 64
    const int om  = bm & 31;

    const int t    = threadIdx.x;
    const int wav  = t >> 6;
    const int lane = t & 63;
    const int l15  = lane & 15;
    const int l4   = lane >> 4;        // 0..3
    const int g    = l4;               // phase 2: owns im 8g..8g+7
    const int od   = l15;

    // ---- B fragments (W) for this wave's 4 N-tiles: lane holds k=(l4)*8+j ----
    // W elem (k=(yx,e), n=(im,od)) at bm*16384 + yx*4096 + im*128 + od*8 + e:
    // for lane l, tile nt: im = wav*4+nt, od = l15, yx = l4, e = j -> 8 contiguous floats.
    bf16x8 wh[4], wl[4];
    {
        const float* wbase = Wt + (size_t)bm * 16384 + (size_t)l4 * 4096 + (size_t)l15 * 8;
        #pragma unroll
        for (int nt = 0; nt < 4; ++nt) {
            const float4* wp = (const float4*)(wbase + (wav * 4 + nt) * 128);
            float4 w0 = wp[0], w1 = wp[1];
            float f[8] = {w0.x, w0.y, w0.z, w0.w, w1.x, w1.y, w1.z, w1.w};
            #pragma unroll
            for (int j = 0; j < 8; ++j) {
                short h = bf_hi(f[j]);
                wh[nt][j] = h;
                wl[nt][j] = bf_hi(f[j] - bf_to_f(h));
            }
        }
    }

    const float* pcb = pc  + (size_t)bm * 8192;   // [k][yx][e] = [256][4][8]
    const float* bLb = bL  + (size_t)om * 8192;   // [k][im]    = [256][32]
    float*       ob  = out + (size_t)bm * 4096;   // [k][od]    = [256][16]

    __shared__ float s_x[16 * XSTR];              // one chunk: 16 tiles x[im,od]

    const int k_lo = ks << 6;

    for (int c = 0; c < 4; ++c) {
        const int k0 = k_lo + (c << 4);
        if (c) __syncthreads();                   // prev chunk's reads done

        // ---- A fragment: lane l holds x_in[k0+(l&15)][(l>>4)*8 + 0..8) ----
        bf16x8 ah, al;
        {
            const float4* ap = (const float4*)(pcb + (size_t)(k0 + l15) * 32 + l4 * 8);
            float4 a0 = ap[0], a1 = ap[1];
            float f[8] = {a0.x, a0.y, a0.z, a0.w, a1.x, a1.y, a1.z, a1.w};
            #pragma unroll
            for (int j = 0; j < 8; ++j) {
                short h = bf_hi(f[j]);
                ah[j] = h;
                al[j] = bf_hi(f[j] - bf_to_f(h));
            }
        }

        // ---- 4 N-tiles: 3 MFMA each (whxh + whxl + wlxh), C -> LDS ----
        #pragma unroll
        for (int nt = 0; nt < 4; ++nt) {
            f32x4 acc = {0.f, 0.f, 0.f, 0.f};
            acc = __builtin_amdgcn_mfma_f32_16x16x32_bf16(ah, wh[nt], acc, 0, 0, 0);
            acc = __builtin_amdgcn_mfma_f32_16x16x32_bf16(al, wh[nt], acc, 0, 0, 0);
            acc = __builtin_amdgcn_mfma_f32_16x16x32_bf16(ah, wl[nt], acc, 0, 0, 0);
            const int n = wav * 64 + nt * 16 + l15;  // C: col = lane&15
            #pragma unroll
            for (int q = 0; q < 4; ++q) {
                const int m = l4 * 4 + q;            // C: row = (lane>>4)*4 + reg
                s_x[m * XSTR + n] = acc[q];
            }
        }

        __syncthreads();

        // ---- phase 2: wave routes tiles m = 2*wav, 2*wav+1 (r2-validated) ----
        #pragma unroll
        for (int half = 0; half < 2; ++half) {
            const int m = wav * 2 + half;
            const int k = k0 + m;

            float xu[8];
            #pragma unroll
            for (int j = 0; j < 8; ++j)
                xu[j] = s_x[m * XSTR + ((g * 8 + j) << 4) + od];

            float bbv[8];
            {
                const float4* bp = (const float4*)(bLb + (k << 5) + (g << 3));
                float4 b0 = bp[0], b1 = bp[1];
                bbv[0]=b0.x; bbv[1]=b0.y; bbv[2]=b0.z; bbv[3]=b0.w;
                bbv[4]=b1.x; bbv[5]=b1.y; bbv[6]=b1.z; bbv[7]=b1.w;
            }

            float vv = 0.f;
            #pragma unroll
            for (int r = 0; r < 3; ++r) {
                float e[8], S = 0.f;
                #pragma unroll
                for (int j = 0; j < 8; ++j) { e[j] = __expf(bbv[j]); S += e[j]; }
                S = gquad_allsum(S);
                float inv = __builtin_amdgcn_rcpf(S);

                vv = 0.f;
                #pragma unroll
                for (int j = 0; j < 8; ++j) vv = fmaf(e[j], xu[j], vv);
                vv = gquad_allsum(vv) * inv;

                float sq = row16_allsum(vv * vv);
                float scale = sq * __builtin_amdgcn_rcpf(1.f + sq) * rsqrtf(sq + EPSF);
                vv *= scale;

                if (r < 2) {
                    #pragma unroll
                    for (int j = 0; j < 8; ++j)
                        bbv[j] += row16_allsum(xu[j] * vv);
                }
            }

            if (g == 0) ob[(k << 4) + od] = vv;
        }
    }
}

extern "C" void kernel_launch(void* const* d_in, const int* in_sizes, int n_in,
                              void* d_out, int out_size, void* d_ws, size_t ws_size,
                              hipStream_t stream)
{
    const float* pc = (const float*)d_in[0];
    const float* Wt = (const float*)d_in[1];
    const float* bL = (const float*)d_in[2];
    float*       o  = (float*)d_out;
    caps_fused<<<dim3(1024), dim3(512), 0, stream>>>(pc, Wt, bL, o);
}

// Round 7
// 43.395 us; speedup vs baseline: 3.4992x; 1.2977x over previous
//
#include <hip/hip_runtime.h>

#define EPSF 1e-7f

typedef short bf16x8 __attribute__((ext_vector_type(8)));
typedef float f32x4  __attribute__((ext_vector_type(4)));

__device__ __forceinline__ short bf_hi(float f) {
    return (short)(__float_as_uint(f) >> 16);        // truncation; residual exact in f32
}
__device__ __forceinline__ float bf_to_f(short h) {
    return __uint_as_float(((unsigned)(unsigned short)h) << 16);
}

template<int CTRL>
__device__ __forceinline__ float dpp_add(float x) {
    int sh = __builtin_amdgcn_update_dpp(0, __float_as_int(x), CTRL, 0xF, 0xF, true);
    return x + __int_as_float(sh);
}
// all-reduce over lane bits 0..3 (16-lane DPP row): xor1,2,7,15 span GF(2)^4.
// (validated r2-r5)
__device__ __forceinline__ float row16_allsum(float x) {
    x = dpp_add<0xB1>(x);   // xor 1
    x = dpp_add<0x4E>(x);   // xor 2
    x = dpp_add<0x141>(x);  // xor 7
    x = dpp_add<0x140>(x);  // xor 15
    return x;
}
// all-reduce over lane bits 4,5 — r2/r5-VALIDATED primitives (ds_swizzle + bpermute).
// r6's permlane16/32_swap version failed correctness; reverted to known-good.
__device__ __forceinline__ float oquad_allsum(float x) {
    x += __int_as_float(__builtin_amdgcn_ds_swizzle(__float_as_int(x), 0x401F)); // xor16
    x += __shfl_xor(x, 32, 64);                                                  // xor32
    return x;
}

// LDS layout: s_x[k][im][od], k-stride 644 words, im-stride 20 words, od direct.
// C-store: banks = 16*(l4&1) + l15 -> 2-way (free). Routing b128 reads: start bank
// 8*(i4&3)+4*o2 -> 8 words/bank, balanced. 16*644*4 = 41216 B.
#define KSTR 644
#define IMSTR 20

// B=8, predict-m=32, K=256, routing-im=32, OD=16, contraction (yx,e)=32.
// Grid: 1024 blocks = 256 (b*32+m) x 4 k-slices of 64. Block: 512 threads (8 waves).
// Phase 1 (16-k chunk): mfma_f32_16x16x32_bf16, 3-term hi/lo split (r5-validated).
// Phase 2: wave routes tiles 2w,2w+1. lane = i4 | (o2<<4): i4 owns im {2i4,2i4+1},
//          o2 owns od {4o2..4o2+3}. im-reduce = row16 DPP; od-reduce = swizzle pair.
__global__ __launch_bounds__(512, 4)
void caps_fused(const float* __restrict__ pc,   // [8,32,32,32,8]
                const float* __restrict__ Wt,   // [8,32,1,2,2,32,16,8]
                const float* __restrict__ bL,   // [1,32,16,16,32]
                float* __restrict__ out)        // [8,32,16,16,16]
{
    const int bid = blockIdx.x;
    const int bm  = bid >> 2;          // b*32 + m
    const int ks  = bid & 3;           // k-slice of 64
    const int om  = bm & 31;

    const int t    = threadIdx.x;
    const int wav  = t >> 6;
    const int lane = t & 63;
    const int l15  = lane & 15;
    const int l4   = lane >> 4;        // 0..3
    const int i4   = l15;              // phase 2: owns im {2*i4, 2*i4+1}
    const int o2   = l4;               // phase 2: owns od {4*o2 .. 4*o2+3}

    // ---- B fragments (W), wave's 4 N-tiles; lane holds k=(l4)*8+j (r5-validated) ----
    bf16x8 wh[4], wl[4];
    {
        const float* wbase = Wt + (size_t)bm * 16384 + (size_t)l4 * 4096 + (size_t)l15 * 8;
        #pragma unroll
        for (int nt = 0; nt < 4; ++nt) {
            const float4* wp = (const float4*)(wbase + (wav * 4 + nt) * 128);
            float4 w0 = wp[0], w1 = wp[1];
            float f[8] = {w0.x, w0.y, w0.z, w0.w, w1.x, w1.y, w1.z, w1.w};
            #pragma unroll
            for (int j = 0; j < 8; ++j) {
                short h = bf_hi(f[j]);
                wh[nt][j] = h;
                wl[nt][j] = bf_hi(f[j] - bf_to_f(h));
            }
        }
    }

    const float* pcb = pc  + (size_t)bm * 8192;   // [k][yx][e] = [256][4][8]
    const float* bLb = bL  + (size_t)om * 8192;   // [k][im]    = [256][32]
    float*       ob  = out + (size_t)bm * 4096;   // [k][od]    = [256][16]

    __shared__ float s_x[16 * KSTR];

    const int k_lo = ks << 6;

    // A-fragment raw loads for chunk 0 (lane l: x_in[k0+l15][l4*8 + 0..8))
    float4 a0, a1;
    {
        const float4* ap = (const float4*)(pcb + (size_t)(k_lo + l15) * 32 + l4 * 8);
        a0 = ap[0]; a1 = ap[1];
    }

    for (int c = 0; c < 4; ++c) {
        const int k0 = k_lo + (c << 4);
        if (c) __syncthreads();                   // prev chunk's routing reads done

        // ---- convert A to bf16 hi/lo ----
        bf16x8 ah, al;
        {
            float f[8] = {a0.x, a0.y, a0.z, a0.w, a1.x, a1.y, a1.z, a1.w};
            #pragma unroll
            for (int j = 0; j < 8; ++j) {
                short h = bf_hi(f[j]);
                ah[j] = h;
                al[j] = bf_hi(f[j] - bf_to_f(h));
            }
        }

        // ---- 4 N-tiles: 3 MFMA each, C -> LDS [k][im][od] ----
        #pragma unroll
        for (int nt = 0; nt < 4; ++nt) {
            f32x4 acc = {0.f, 0.f, 0.f, 0.f};
            acc = __builtin_amdgcn_mfma_f32_16x16x32_bf16(ah, wh[nt], acc, 0, 0, 0);
            acc = __builtin_amdgcn_mfma_f32_16x16x32_bf16(al, wh[nt], acc, 0, 0, 0);
            acc = __builtin_amdgcn_mfma_f32_16x16x32_bf16(ah, wl[nt], acc, 0, 0, 0);
            const int im = wav * 4 + nt;              // C col-block = im, col = od = l15
            #pragma unroll
            for (int q = 0; q < 4; ++q) {
                const int kr = l4 * 4 + q;            // C row = k
                s_x[kr * KSTR + im * IMSTR + l15] = acc[q];
            }
        }

        // ---- prefetch next chunk's A (overlaps routing) ----
        if (c < 3) {
            const float4* ap = (const float4*)(pcb + (size_t)(k0 + 16 + l15) * 32 + l4 * 8);
            a0 = ap[0]; a1 = ap[1];
        }

        // ---- preload routing logits for both tiles ----
        const int ka = k0 + 2 * wav, kb = ka + 1;
        float2 bba = *(const float2*)(bLb + (ka << 5) + 2 * i4);
        float2 bbb = *(const float2*)(bLb + (kb << 5) + 2 * i4);

        __syncthreads();

        // ---- phase 2: route tiles ka, kb ----
        #pragma unroll
        for (int half = 0; half < 2; ++half) {
            const int k  = half ? kb : ka;
            const int kl = 2 * wav + half;
            const float* xp = &s_x[kl * KSTR + i4 * (2 * IMSTR) + 4 * o2];
            const float4 xa = *(const float4*)xp;            // x[2i4  ][4o2..]
            const float4 xb = *(const float4*)(xp + IMSTR);  // x[2i4+1][4o2..]
            float b0 = half ? bbb.x : bba.x;
            float b1 = half ? bbb.y : bba.y;

            float v0, v1, v2, v3;
            #pragma unroll
            for (int r = 0; r < 3; ++r) {
                float e0 = __expf(b0), e1 = __expf(b1);
                float S  = row16_allsum(e0 + e1);            // softmax denom over 32 im
                float inv = __builtin_amdgcn_rcpf(S);

                v0 = row16_allsum(fmaf(e0, xa.x, e1 * xb.x)) * inv;
                v1 = row16_allsum(fmaf(e0, xa.y, e1 * xb.y)) * inv;
                v2 = row16_allsum(fmaf(e0, xa.z, e1 * xb.z)) * inv;
                v3 = row16_allsum(fmaf(e0, xa.w, e1 * xb.w)) * inv;

                float sq = oquad_allsum(fmaf(v0, v0, fmaf(v1, v1, fmaf(v2, v2, v3 * v3))));
                float scale = sq * __builtin_amdgcn_rcpf(1.f + sq) * rsqrtf(sq + EPSF);
                v0 *= scale; v1 *= scale; v2 *= scale; v3 *= scale;

                if (r < 2) {
                    float d0 = oquad_allsum(fmaf(xa.x, v0, fmaf(xa.y, v1, fmaf(xa.z, v2, xa.w * v3))));
                    float d1 = oquad_allsum(fmaf(xb.x, v0, fmaf(xb.y, v1, fmaf(xb.z, v2, xb.w * v3))));
                    b0 += d0; b1 += d1;
                }
            }

            if (i4 == 0)
                *(float4*)(ob + (k << 4) + 4 * o2) = make_float4(v0, v1, v2, v3);
        }
    }
}

extern "C" void kernel_launch(void* const* d_in, const int* in_sizes, int n_in,
                              void* d_out, int out_size, void* d_ws, size_t ws_size,
                              hipStream_t stream)
{
    const float* pc = (const float*)d_in[0];
    const float* Wt = (const float*)d_in[1];
    const float* bL = (const float*)d_in[2];
    float*       o  = (float*)d_out;
    caps_fused<<<dim3(1024), dim3(512), 0, stream>>>(pc, Wt, bL, o);
}